// Round 6
// baseline (591.595 us; speedup 1.0000x reference)
//
#include <hip/hip_runtime.h>
#include <hip/hip_bf16.h>

#define H 128
#define CAP 64          // bucket capacity (avg degree 16; P(deg>64) ~ 1e-20)
#define CNT_SCALE 16777216.0   // 2^24: dsum double encodes cnt*2^24 + sum_w

typedef __attribute__((ext_vector_type(8))) short bf16x8;
typedef __attribute__((ext_vector_type(4))) float f32x4;

__device__ __forceinline__ unsigned short f2b(float f) {
  __hip_bfloat16 h = __float2bfloat16(f);
  union { __hip_bfloat16 h; unsigned short u; } c; c.h = h; return c.u;
}
__device__ __forceinline__ float b2f(unsigned short u) {
  union { unsigned int i; float f; } c; c.i = (unsigned)u << 16; return c.f;
}

// ---------------- build: one fused atomic per edge gives slot AND degree-sum ----------------

__global__ void k_fillb2(const int* __restrict__ row, const int* __restrict__ col,
                         const float* __restrict__ ew, double* __restrict__ dsum,
                         int2* __restrict__ elist, int E) {
  int e = blockIdx.x * 256 + threadIdx.x;
  if (e >= E) return;
  int c = col[e];
  float w = ew[e];
  double old = atomicAdd(&dsum[c], (double)w + CNT_SCALE);
  int pos = (int)(old * (1.0 / CNT_SCALE));   // sum_w_so_far << 2^24, floor safe
  if (pos < CAP) elist[(size_t)c * CAP + pos] = make_int2(row[e], __float_as_int(w));
}

__global__ void k_dinv(const double* __restrict__ dsum, float* __restrict__ dinv,
                       int* __restrict__ cnt, int n) {
  int i = blockIdx.x * 256 + threadIdx.x;
  if (i >= n) return;
  double v = dsum[i];
  double c = floor(v * (1.0 / CNT_SCALE));
  double s = v - c * CNT_SCALE + 1.0;          // + self-loop weight
  dinv[i] = (float)(1.0 / sqrt(s));
  cnt[i] = (int)c;
}

// ---------------- W prep: transpose + bf16 hi/lo split (3 layers in one launch) ----------------

__global__ void k_wprep(const float* __restrict__ W0, const float* __restrict__ W1,
                        const float* __restrict__ W2, unsigned short* __restrict__ th,
                        unsigned short* __restrict__ tl) {
  int i = blockIdx.x * 256 + threadIdx.x;    // grid covers exactly 3*H*H
  int m = i >> 14;                           // which matrix
  int r = i & 16383;
  const float* W = m == 0 ? W0 : (m == 1 ? W1 : W2);
  int k = r >> 7, n = r & 127;
  float w = W[r];                            // W[k][n]
  unsigned short hi = f2b(w);
  th[(size_t)m * H * H + n * H + k] = hi;    // Wt[n][k]
  tl[(size_t)m * H * H + n * H + k] = f2b(w - b2f(hi));
}

// ---------------- GEMM via MFMA bf16 hi/lo split: Y = X @ W (+bias, relu) ----------------
// wave owns 16 rows; A-frag: m=lane&15, k=8*(lane>>4)+j; B-frag from Wt[n][k] rows;
// C: col=lane&15, row=4*(lane>>4)+reg (m89-verified layout).

__global__ __launch_bounds__(256) void k_gemm_mfma(const float* __restrict__ X,
    const unsigned short* __restrict__ WH, const unsigned short* __restrict__ WL,
    void* __restrict__ Yv, int Nrows, const float* __restrict__ bias,
    int relu, int outbf) {
  int wave = threadIdx.x >> 6;
  int lane = threadIdx.x & 63;
  int mrow = lane & 15;
  int h    = lane >> 4;
  int Mbase = blockIdx.x * 64 + wave * 16;
  int arow = Mbase + mrow;
  if (arow >= Nrows) arow = Nrows - 1;       // clamp reads; stores predicated
  const float* xr = X + (size_t)arow * H;
  bf16x8 ahi[4], alo[4];
  #pragma unroll
  for (int kt = 0; kt < 4; ++kt) {
    int k0 = kt * 32 + h * 8;
    float4 f0 = *(const float4*)(xr + k0);
    float4 f1 = *(const float4*)(xr + k0 + 4);
    float fs0 = f0.x, fs1 = f0.y, fs2 = f0.z, fs3 = f0.w;
    float fs4 = f1.x, fs5 = f1.y, fs6 = f1.z, fs7 = f1.w;
    #define SPLIT(J, V) { unsigned short hi_ = f2b(V); \
      ((short*)&ahi[kt])[J] = (short)hi_; \
      ((short*)&alo[kt])[J] = (short)f2b((V) - b2f(hi_)); }
    SPLIT(0, fs0) SPLIT(1, fs1) SPLIT(2, fs2) SPLIT(3, fs3)
    SPLIT(4, fs4) SPLIT(5, fs5) SPLIT(6, fs6) SPLIT(7, fs7)
    #undef SPLIT
  }
  #pragma unroll
  for (int nt = 0; nt < 8; ++nt) {
    f32x4 acc = {0.f, 0.f, 0.f, 0.f};
    #pragma unroll
    for (int kt = 0; kt < 4; ++kt) {
      size_t boff = (size_t)(nt * 16 + mrow) * H + kt * 32 + h * 8;
      bf16x8 bh = *(const bf16x8*)(WH + boff);
      bf16x8 bl = *(const bf16x8*)(WL + boff);
      acc = __builtin_amdgcn_mfma_f32_16x16x32_bf16(ahi[kt], bh, acc, 0, 0, 0);
      acc = __builtin_amdgcn_mfma_f32_16x16x32_bf16(alo[kt], bh, acc, 0, 0, 0);
      acc = __builtin_amdgcn_mfma_f32_16x16x32_bf16(ahi[kt], bl, acc, 0, 0, 0);
    }
    int ocol = nt * 16 + mrow;
    float bb = bias ? bias[ocol] : 0.f;
    #pragma unroll
    for (int r = 0; r < 4; ++r) {
      int orow = Mbase + 4 * h + r;
      if (orow < Nrows) {
        float v = acc[r] + bb;
        if (relu) v = fmaxf(v, 0.f);
        if (outbf) ((unsigned short*)Yv)[(size_t)orow * H + ocol] = f2b(v);
        else       ((float*)Yv)[(size_t)orow * H + ocol] = v;
      }
    }
  }
}

// ---------------- Aggregation from bf16 rows (256B/row), norm on the fly ----------------

__global__ __launch_bounds__(256) void k_aggb(const unsigned short* __restrict__ XWB,
    const int2* __restrict__ elist, const int* __restrict__ cnt,
    const float* __restrict__ dinv, const float* __restrict__ bias,
    float* __restrict__ out, int n, int relu) {
  int wid = (blockIdx.x * 256 + threadIdx.x) >> 6;
  if (wid >= n) return;
  int lane = threadIdx.x & 63;
  int half = lane >> 5;
  int c4 = lane & 31;
  const ushort4* xw4 = (const ushort4*)XWB;   // row = 32 ushort4
  int m = min(cnt[wid], CAP);
  int mh = (m - half + 1) >> 1;
  const int2* ep = elist + (size_t)wid * CAP + half;
  float dc = dinv[wid];
  float4 acc;
  if (half == 0) {
    float d2 = dc * dc;
    ushort4 s = xw4[(size_t)wid * 32 + c4];
    acc = make_float4(d2 * b2f(s.x), d2 * b2f(s.y), d2 * b2f(s.z), d2 * b2f(s.w));
  } else {
    acc = make_float4(0.f, 0.f, 0.f, 0.f);
  }
  for (int j0 = 0; j0 < mh; j0 += 8) {
    int2 Ee[8];
    #pragma unroll
    for (int u = 0; u < 8; ++u) {
      int j = j0 + u;
      Ee[u] = (j < mh) ? ep[2 * j] : make_int2(0, 0);
    }
    float dv[8];
    #pragma unroll
    for (int u = 0; u < 8; ++u) dv[u] = dinv[Ee[u].x];
    ushort4 V[8];
    #pragma unroll
    for (int u = 0; u < 8; ++u) V[u] = xw4[(size_t)Ee[u].x * 32 + c4];
    #pragma unroll
    for (int u = 0; u < 8; ++u) {
      float nn = dv[u] * __int_as_float(Ee[u].y) * dc;
      acc.x = fmaf(nn, b2f(V[u].x), acc.x);
      acc.y = fmaf(nn, b2f(V[u].y), acc.y);
      acc.z = fmaf(nn, b2f(V[u].z), acc.z);
      acc.w = fmaf(nn, b2f(V[u].w), acc.w);
    }
  }
  acc.x += __shfl_xor(acc.x, 32);
  acc.y += __shfl_xor(acc.y, 32);
  acc.z += __shfl_xor(acc.z, 32);
  acc.w += __shfl_xor(acc.w, 32);
  if (half == 0) {
    float4 bb = ((const float4*)bias)[c4];
    acc.x += bb.x; acc.y += bb.y; acc.z += bb.z; acc.w += bb.w;
    if (relu) {
      acc.x = fmaxf(acc.x, 0.f); acc.y = fmaxf(acc.y, 0.f);
      acc.z = fmaxf(acc.z, 0.f); acc.w = fmaxf(acc.w, 0.f);
    }
    ((float4*)out)[(size_t)wid * 32 + c4] = acc;
  }
}

// ---------------- Layer-0 aggregation in embedding space (fp32 ztab, L2-resident) ----------------

#define EFMA(nn, vv) { acc.x = fmaf(nn, vv.x, acc.x); acc.y = fmaf(nn, vv.y, acc.y); \
                       acc.z = fmaf(nn, vv.z, acc.z); acc.w = fmaf(nn, vv.w, acc.w); }

__global__ __launch_bounds__(256) void k_agg_emb(const float* __restrict__ ZT,
    const int* __restrict__ z, const int2* __restrict__ elist, const int* __restrict__ cnt,
    const float* __restrict__ dinv, float* __restrict__ out, int n) {
  int wid = (blockIdx.x * 256 + threadIdx.x) >> 6;
  if (wid >= n) return;
  int lane = threadIdx.x & 63;
  int half = lane >> 5;
  int c4 = lane & 31;
  const float4* zt4 = (const float4*)ZT;
  int m = min(cnt[wid], CAP);
  int mh = (m - half + 1) >> 1;
  const int2* ep = elist + (size_t)wid * CAP + half;
  float dc = dinv[wid];
  float4 acc;
  if (half == 0) {
    float d2 = dc * dc;
    float4 s = zt4[(size_t)z[wid] * 32 + c4];
    acc = make_float4(d2 * s.x, d2 * s.y, d2 * s.z, d2 * s.w);
  } else {
    acc = make_float4(0.f, 0.f, 0.f, 0.f);
  }
  for (int j0 = 0; j0 < mh; j0 += 8) {
    int2 Ee[8];
    #pragma unroll
    for (int u = 0; u < 8; ++u) {
      int j = j0 + u;
      Ee[u] = (j < mh) ? ep[2 * j] : make_int2(0, 0);
    }
    int zr[8]; float dv[8];
    #pragma unroll
    for (int u = 0; u < 8; ++u) { zr[u] = z[Ee[u].x]; dv[u] = dinv[Ee[u].x]; }
    float4 V[8];
    #pragma unroll
    for (int u = 0; u < 8; ++u) V[u] = zt4[(size_t)zr[u] * 32 + c4];
    #pragma unroll
    for (int u = 0; u < 8; ++u) {
      float nn = dv[u] * __int_as_float(Ee[u].y) * dc;
      EFMA(nn, V[u])
    }
  }
  acc.x += __shfl_xor(acc.x, 32);
  acc.y += __shfl_xor(acc.y, 32);
  acc.z += __shfl_xor(acc.z, 32);
  acc.w += __shfl_xor(acc.w, 32);
  if (half == 0) ((float4*)out)[(size_t)wid * 32 + c4] = acc;
}

// ---------------- Head ----------------

__global__ __launch_bounds__(128) void k_head(const float* __restrict__ X,
    const int* __restrict__ batch, int n,
    const float* __restrict__ W1, const float* __restrict__ b1,
    const float* __restrict__ W2, const float* __restrict__ b2,
    float* __restrict__ out, int G) {
  int g = blockIdx.x, t = threadIdx.x;
  int lo = 0, hi = n;
  while (lo < hi) { int mid = (lo + hi) >> 1; if (batch[mid] < g) lo = mid + 1; else hi = mid; }
  __shared__ float hs[H];
  hs[t] = X[(size_t)lo * H + t] * X[(size_t)(lo + 1) * H + t];
  __syncthreads();
  float a = b1[t];
  #pragma unroll 8
  for (int k = 0; k < H; ++k) a = fmaf(hs[k], W1[k * H + t], a);
  a = fmaxf(a, 0.f);
  a *= W2[t];
  for (int off = 32; off > 0; off >>= 1) a += __shfl_down(a, off);
  __shared__ float wsum[2];
  if ((t & 63) == 0) wsum[t >> 6] = a;
  __syncthreads();
  if (t == 0) out[g] = wsum[0] + wsum[1] + b2[0];
}

// ---------------- launch ----------------

extern "C" void kernel_launch(void* const* d_in, const int* in_sizes, int n_in,
                              void* d_out, int out_size, void* d_ws, size_t ws_size,
                              hipStream_t stream) {
  const int* z     = (const int*)d_in[0];
  const int* eidx  = (const int*)d_in[1];
  const int* batch = (const int*)d_in[2];
  const float* ew  = (const float*)d_in[3];
  const float* ztab= (const float*)d_in[4];
  const float *W0, *W1, *W2, *b0, *b1, *b2, *l1W, *l1b, *l2W, *l2b;
  if (n_in >= 15) {
    W0 = (const float*)d_in[5];  W1 = (const float*)d_in[6];  W2 = (const float*)d_in[7];
    b0 = (const float*)d_in[8];  b1 = (const float*)d_in[9];  b2 = (const float*)d_in[10];
    l1W = (const float*)d_in[11]; l1b = (const float*)d_in[12];
    l2W = (const float*)d_in[13]; l2b = (const float*)d_in[14];
  } else {
    const float* Wss = (const float*)d_in[5];
    W0 = Wss; W1 = Wss + H * H; W2 = Wss + 2 * H * H;
    const float* bs = (const float*)d_in[6];
    b0 = bs; b1 = bs + H; b2 = bs + 2 * H;
    l1W = (const float*)d_in[7]; l1b = (const float*)d_in[8];
    l2W = (const float*)d_in[9]; l2b = (const float*)d_in[10];
  }
  int N = in_sizes[0];
  int E = in_sizes[3];
  int G = out_size;
  float* fout = (float*)d_out;

  size_t woff = 0;
  auto alloc = [&](size_t bytes) {
    void* p = (char*)d_ws + woff;
    woff += (bytes + 255) & ~(size_t)255;
    return p;
  };
  float*          bufA  = (float*)alloc((size_t)N * H * 4);
  float*          bufB  = (float*)alloc((size_t)N * H * 4);   // also layer-0 temp (xw)
  unsigned short* xwb   = (unsigned short*)alloc((size_t)N * H * 2);
  double*         dsum  = (double*)alloc((size_t)N * 8);
  float*          dinv  = (float*)alloc((size_t)N * 4);
  int*            cnt   = (int*)alloc((size_t)N * 4);
  unsigned short* wth   = (unsigned short*)alloc((size_t)3 * H * H * 2);
  unsigned short* wtl   = (unsigned short*)alloc((size_t)3 * H * H * 2);
  int2*           elist = (int2*)alloc((size_t)N * CAP * 8);
  float*          xw    = bufB;   // layer-0 fp32 temp aliases bufB

  const int* erow = eidx;
  const int* ecol = eidx + E;

  hipMemsetAsync(dsum, 0, (size_t)N * 8, stream);

  int nb = (N + 255) / 256;
  int eb = (E + 255) / 256;
  int wgrid = (N + 3) / 4;
  int ggrid = (N + 63) / 64;

  k_fillb2<<<eb, 256, 0, stream>>>(erow, ecol, ew, dsum, elist, E);
  k_dinv<<<nb, 256, 0, stream>>>(dsum, dinv, cnt, N);
  k_wprep<<<3 * H * H / 256, 256, 0, stream>>>(W0, W1, W2, wth, wtl);

  // layer 0: aggregate embeddings first (L2-resident gather), then MFMA GEMM+bias+relu
  k_agg_emb<<<wgrid, 256, 0, stream>>>(ztab, z, elist, cnt, dinv, xw, N);
  k_gemm_mfma<<<ggrid, 256, 0, stream>>>(xw, wth, wtl, bufA, N, b0, 1, 0);
  // layer 1: MFMA GEMM -> bf16 gather buffer -> aggregate
  k_gemm_mfma<<<ggrid, 256, 0, stream>>>(bufA, wth + H * H, wtl + H * H, xwb, N, nullptr, 0, 1);
  k_aggb<<<wgrid, 256, 0, stream>>>(xwb, elist, cnt, dinv, b1, bufB, N, 1);
  // layer 2
  k_gemm_mfma<<<ggrid, 256, 0, stream>>>(bufB, wth + 2 * H * H, wtl + 2 * H * H, xwb, N, nullptr, 0, 1);
  k_aggb<<<wgrid, 256, 0, stream>>>(xwb, elist, cnt, dinv, b2, bufA, N, 0);

  k_head<<<G, 128, 0, stream>>>(bufA, batch, N, l1W, l1b, l2W, l2b, fout, G);
}

// Round 7
// 527.048 us; speedup vs baseline: 1.1225x; 1.1225x over previous
//
#include <hip/hip_runtime.h>
#include <hip/hip_bf16.h>

#define H 128
#define CAP 64          // bucket capacity (avg degree 16; P(deg>64) ~ 1e-20)
#define GBM 64
#define GBN 64
#define NSWEEP 8        // fillb2 sweeps by col high-bits (temporal atomic clustering)
#define CNT_SCALE 16777216.0   // 2^24: dsum double encodes cnt*2^24 + sum_w

__device__ __forceinline__ unsigned short f2b(float f) {
  __hip_bfloat16 h = __float2bfloat16(f);
  union { __hip_bfloat16 h; unsigned short u; } c; c.h = h; return c.u;
}
__device__ __forceinline__ float b2f(unsigned short u) {
  union { unsigned int i; float f; } c; c.i = (unsigned)u << 16; return c.f;
}

// ---------------- build: one fused atomic per edge; sweeps cluster same-line atomics ----------------
// blockIdx.z = sweep s; only edges whose col falls in sweep-s range are committed.
// eb padded to multiple of 8 so chunk b maps to the same XCD every sweep (L2-warm re-reads).

__global__ void k_fillb2(const int* __restrict__ row, const int* __restrict__ col,
                         const float* __restrict__ ew, double* __restrict__ dsum,
                         int2* __restrict__ elist, int E, int shift) {
  int e = blockIdx.x * 256 + threadIdx.x;
  if (e >= E) return;
  int c = col[e];
  float w = ew[e];
  if ((c >> shift) != (int)blockIdx.z) return;   // not this sweep
  double old = atomicAdd(&dsum[c], (double)w + CNT_SCALE);
  int pos = (int)(old * (1.0 / CNT_SCALE));      // sum_w_so_far << 2^24, floor safe
  if (pos < CAP) elist[(size_t)c * CAP + pos] = make_int2(row[e], __float_as_int(w));
}

__global__ void k_dinv(const double* __restrict__ dsum, float* __restrict__ dinv,
                       int* __restrict__ cnt, int n) {
  int i = blockIdx.x * 256 + threadIdx.x;
  if (i >= n) return;
  double v = dsum[i];
  double c = floor(v * (1.0 / CNT_SCALE));
  double s = v - c * CNT_SCALE + 1.0;          // + self-loop weight
  dinv[i] = (float)(1.0 / sqrt(s));
  cnt[i] = (int)c;
}

// ---------------- GEMM: Y = X @ W (+bias, relu), output fp32 or bf16 (VALU, 64x64 tile) ----------------

#define FMA4(A, xs, wv) { A[0] = fmaf(xs, wv.x, A[0]); A[1] = fmaf(xs, wv.y, A[1]); \
                          A[2] = fmaf(xs, wv.z, A[2]); A[3] = fmaf(xs, wv.w, A[3]); }

__global__ __launch_bounds__(256, 2) void k_gemm(const float* __restrict__ X,
    const float* __restrict__ Wg, void* __restrict__ Yv, int Nrows,
    const float* __restrict__ bias, int relu, int outbf) {
  __shared__ float Ws[H][GBN + 4];
  int tid = threadIdx.x;
  int bm = blockIdx.x * GBM;
  int bn = blockIdx.y * GBN;
  for (int i = tid; i < H * (GBN / 4); i += 256) {
    int k = i >> 4, c4 = (i & 15) * 4;
    *(float4*)&Ws[k][c4] = *(const float4*)(Wg + k * H + bn + c4);
  }
  __syncthreads();
  int rg = tid >> 4, cg = tid & 15;
  int cg4 = cg * 4;
  int g0 = bm + rg * 4 + 0, g1 = g0 + 1, g2 = g0 + 2, g3 = g0 + 3;
  const float* xp0; const float* xp1; const float* xp2; const float* xp3;
  {
    int c0 = g0 < Nrows ? g0 : Nrows - 1;
    int c1 = g1 < Nrows ? g1 : Nrows - 1;
    int c2 = g2 < Nrows ? g2 : Nrows - 1;
    int c3 = g3 < Nrows ? g3 : Nrows - 1;
    xp0 = X + (size_t)c0 * H; xp1 = X + (size_t)c1 * H;
    xp2 = X + (size_t)c2 * H; xp3 = X + (size_t)c3 * H;
  }
  float a0[4] = {0,0,0,0}, a1[4] = {0,0,0,0}, a2[4] = {0,0,0,0}, a3[4] = {0,0,0,0};
  #pragma unroll 2
  for (int k = 0; k < H; k += 4) {
    float4 x0 = *(const float4*)(xp0 + k);
    float4 x1 = *(const float4*)(xp1 + k);
    float4 x2 = *(const float4*)(xp2 + k);
    float4 x3 = *(const float4*)(xp3 + k);
    float4 w0 = *(const float4*)&Ws[k + 0][cg4];
    float4 w1 = *(const float4*)&Ws[k + 1][cg4];
    float4 w2 = *(const float4*)&Ws[k + 2][cg4];
    float4 w3 = *(const float4*)&Ws[k + 3][cg4];
    FMA4(a0, x0.x, w0) FMA4(a0, x0.y, w1) FMA4(a0, x0.z, w2) FMA4(a0, x0.w, w3)
    FMA4(a1, x1.x, w0) FMA4(a1, x1.y, w1) FMA4(a1, x1.z, w2) FMA4(a1, x1.w, w3)
    FMA4(a2, x2.x, w0) FMA4(a2, x2.y, w1) FMA4(a2, x2.z, w2) FMA4(a2, x2.w, w3)
    FMA4(a3, x3.x, w0) FMA4(a3, x3.y, w1) FMA4(a3, x3.z, w2) FMA4(a3, x3.w, w3)
  }
  if (bias) {
    float4 bb = *(const float4*)(bias + bn + cg4);
    #pragma unroll
    for (int u = 0; u < 4; ++u) {
      a0[u] += ((const float*)&bb)[u]; a1[u] += ((const float*)&bb)[u];
      a2[u] += ((const float*)&bb)[u]; a3[u] += ((const float*)&bb)[u];
    }
  }
  if (relu) {
    #pragma unroll
    for (int u = 0; u < 4; ++u) {
      a0[u] = fmaxf(a0[u], 0.f); a1[u] = fmaxf(a1[u], 0.f);
      a2[u] = fmaxf(a2[u], 0.f); a3[u] = fmaxf(a3[u], 0.f);
    }
  }
  if (outbf) {
    unsigned short* Yb = (unsigned short*)Yv;
    ushort4 h0 = make_ushort4(f2b(a0[0]), f2b(a0[1]), f2b(a0[2]), f2b(a0[3]));
    ushort4 h1 = make_ushort4(f2b(a1[0]), f2b(a1[1]), f2b(a1[2]), f2b(a1[3]));
    ushort4 h2 = make_ushort4(f2b(a2[0]), f2b(a2[1]), f2b(a2[2]), f2b(a2[3]));
    ushort4 h3 = make_ushort4(f2b(a3[0]), f2b(a3[1]), f2b(a3[2]), f2b(a3[3]));
    if (g0 < Nrows) *(ushort4*)(Yb + (size_t)g0 * H + bn + cg4) = h0;
    if (g1 < Nrows) *(ushort4*)(Yb + (size_t)g1 * H + bn + cg4) = h1;
    if (g2 < Nrows) *(ushort4*)(Yb + (size_t)g2 * H + bn + cg4) = h2;
    if (g3 < Nrows) *(ushort4*)(Yb + (size_t)g3 * H + bn + cg4) = h3;
  } else {
    float* Y = (float*)Yv;
    if (g0 < Nrows) *(float4*)(Y + (size_t)g0 * H + bn + cg4) = make_float4(a0[0], a0[1], a0[2], a0[3]);
    if (g1 < Nrows) *(float4*)(Y + (size_t)g1 * H + bn + cg4) = make_float4(a1[0], a1[1], a1[2], a1[3]);
    if (g2 < Nrows) *(float4*)(Y + (size_t)g2 * H + bn + cg4) = make_float4(a2[0], a2[1], a2[2], a2[3]);
    if (g3 < Nrows) *(float4*)(Y + (size_t)g3 * H + bn + cg4) = make_float4(a3[0], a3[1], a3[2], a3[3]);
  }
}

// ---------------- Aggregation from bf16 rows (256B/row), norm on the fly ----------------

__global__ __launch_bounds__(256) void k_aggb(const unsigned short* __restrict__ XWB,
    const int2* __restrict__ elist, const int* __restrict__ cnt,
    const float* __restrict__ dinv, const float* __restrict__ bias,
    float* __restrict__ out, int n, int relu) {
  int wid = (blockIdx.x * 256 + threadIdx.x) >> 6;
  if (wid >= n) return;
  int lane = threadIdx.x & 63;
  int half = lane >> 5;
  int c4 = lane & 31;
  const ushort4* xw4 = (const ushort4*)XWB;   // row = 32 ushort4
  int m = min(cnt[wid], CAP);
  int mh = (m - half + 1) >> 1;
  const int2* ep = elist + (size_t)wid * CAP + half;
  float dc = dinv[wid];
  float4 acc;
  if (half == 0) {
    float d2 = dc * dc;
    ushort4 s = xw4[(size_t)wid * 32 + c4];
    acc = make_float4(d2 * b2f(s.x), d2 * b2f(s.y), d2 * b2f(s.z), d2 * b2f(s.w));
  } else {
    acc = make_float4(0.f, 0.f, 0.f, 0.f);
  }
  for (int j0 = 0; j0 < mh; j0 += 8) {
    int2 Ee[8];
    #pragma unroll
    for (int u = 0; u < 8; ++u) {
      int j = j0 + u;
      Ee[u] = (j < mh) ? ep[2 * j] : make_int2(0, 0);
    }
    float dv[8];
    #pragma unroll
    for (int u = 0; u < 8; ++u) dv[u] = dinv[Ee[u].x];
    ushort4 V[8];
    #pragma unroll
    for (int u = 0; u < 8; ++u) V[u] = xw4[(size_t)Ee[u].x * 32 + c4];
    #pragma unroll
    for (int u = 0; u < 8; ++u) {
      float nn = dv[u] * __int_as_float(Ee[u].y) * dc;
      acc.x = fmaf(nn, b2f(V[u].x), acc.x);
      acc.y = fmaf(nn, b2f(V[u].y), acc.y);
      acc.z = fmaf(nn, b2f(V[u].z), acc.z);
      acc.w = fmaf(nn, b2f(V[u].w), acc.w);
    }
  }
  acc.x += __shfl_xor(acc.x, 32);
  acc.y += __shfl_xor(acc.y, 32);
  acc.z += __shfl_xor(acc.z, 32);
  acc.w += __shfl_xor(acc.w, 32);
  if (half == 0) {
    float4 bb = ((const float4*)bias)[c4];
    acc.x += bb.x; acc.y += bb.y; acc.z += bb.z; acc.w += bb.w;
    if (relu) {
      acc.x = fmaxf(acc.x, 0.f); acc.y = fmaxf(acc.y, 0.f);
      acc.z = fmaxf(acc.z, 0.f); acc.w = fmaxf(acc.w, 0.f);
    }
    ((float4*)out)[(size_t)wid * 32 + c4] = acc;
  }
}

// ---------------- Layer-0 aggregation in embedding space (fp32 ztab, L2-resident) ----------------

#define EFMA(nn, vv) { acc.x = fmaf(nn, vv.x, acc.x); acc.y = fmaf(nn, vv.y, acc.y); \
                       acc.z = fmaf(nn, vv.z, acc.z); acc.w = fmaf(nn, vv.w, acc.w); }

__global__ __launch_bounds__(256) void k_agg_emb(const float* __restrict__ ZT,
    const int* __restrict__ z, const int2* __restrict__ elist, const int* __restrict__ cnt,
    const float* __restrict__ dinv, float* __restrict__ out, int n) {
  int wid = (blockIdx.x * 256 + threadIdx.x) >> 6;
  if (wid >= n) return;
  int lane = threadIdx.x & 63;
  int half = lane >> 5;
  int c4 = lane & 31;
  const float4* zt4 = (const float4*)ZT;
  int m = min(cnt[wid], CAP);
  int mh = (m - half + 1) >> 1;
  const int2* ep = elist + (size_t)wid * CAP + half;
  float dc = dinv[wid];
  float4 acc;
  if (half == 0) {
    float d2 = dc * dc;
    float4 s = zt4[(size_t)z[wid] * 32 + c4];
    acc = make_float4(d2 * s.x, d2 * s.y, d2 * s.z, d2 * s.w);
  } else {
    acc = make_float4(0.f, 0.f, 0.f, 0.f);
  }
  for (int j0 = 0; j0 < mh; j0 += 8) {
    int2 Ee[8];
    #pragma unroll
    for (int u = 0; u < 8; ++u) {
      int j = j0 + u;
      Ee[u] = (j < mh) ? ep[2 * j] : make_int2(0, 0);
    }
    int zr[8]; float dv[8];
    #pragma unroll
    for (int u = 0; u < 8; ++u) { zr[u] = z[Ee[u].x]; dv[u] = dinv[Ee[u].x]; }
    float4 V[8];
    #pragma unroll
    for (int u = 0; u < 8; ++u) V[u] = zt4[(size_t)zr[u] * 32 + c4];
    #pragma unroll
    for (int u = 0; u < 8; ++u) {
      float nn = dv[u] * __int_as_float(Ee[u].y) * dc;
      EFMA(nn, V[u])
    }
  }
  acc.x += __shfl_xor(acc.x, 32);
  acc.y += __shfl_xor(acc.y, 32);
  acc.z += __shfl_xor(acc.z, 32);
  acc.w += __shfl_xor(acc.w, 32);
  if (half == 0) ((float4*)out)[(size_t)wid * 32 + c4] = acc;
}

// ---------------- Head ----------------

__global__ __launch_bounds__(128) void k_head(const float* __restrict__ X,
    const int* __restrict__ batch, int n,
    const float* __restrict__ W1, const float* __restrict__ b1,
    const float* __restrict__ W2, const float* __restrict__ b2,
    float* __restrict__ out, int G) {
  int g = blockIdx.x, t = threadIdx.x;
  int lo = 0, hi = n;
  while (lo < hi) { int mid = (lo + hi) >> 1; if (batch[mid] < g) lo = mid + 1; else hi = mid; }
  __shared__ float hs[H];
  hs[t] = X[(size_t)lo * H + t] * X[(size_t)(lo + 1) * H + t];
  __syncthreads();
  float a = b1[t];
  #pragma unroll 8
  for (int k = 0; k < H; ++k) a = fmaf(hs[k], W1[k * H + t], a);
  a = fmaxf(a, 0.f);
  a *= W2[t];
  for (int off = 32; off > 0; off >>= 1) a += __shfl_down(a, off);
  __shared__ float wsum[2];
  if ((t & 63) == 0) wsum[t >> 6] = a;
  __syncthreads();
  if (t == 0) out[g] = wsum[0] + wsum[1] + b2[0];
}

// ---------------- launch ----------------

extern "C" void kernel_launch(void* const* d_in, const int* in_sizes, int n_in,
                              void* d_out, int out_size, void* d_ws, size_t ws_size,
                              hipStream_t stream) {
  const int* z     = (const int*)d_in[0];
  const int* eidx  = (const int*)d_in[1];
  const int* batch = (const int*)d_in[2];
  const float* ew  = (const float*)d_in[3];
  const float* ztab= (const float*)d_in[4];
  const float *W0, *W1, *W2, *b0, *b1, *b2, *l1W, *l1b, *l2W, *l2b;
  if (n_in >= 15) {
    W0 = (const float*)d_in[5];  W1 = (const float*)d_in[6];  W2 = (const float*)d_in[7];
    b0 = (const float*)d_in[8];  b1 = (const float*)d_in[9];  b2 = (const float*)d_in[10];
    l1W = (const float*)d_in[11]; l1b = (const float*)d_in[12];
    l2W = (const float*)d_in[13]; l2b = (const float*)d_in[14];
  } else {
    const float* Wss = (const float*)d_in[5];
    W0 = Wss; W1 = Wss + H * H; W2 = Wss + 2 * H * H;
    const float* bs = (const float*)d_in[6];
    b0 = bs; b1 = bs + H; b2 = bs + 2 * H;
    l1W = (const float*)d_in[7]; l1b = (const float*)d_in[8];
    l2W = (const float*)d_in[9]; l2b = (const float*)d_in[10];
  }
  int N = in_sizes[0];
  int E = in_sizes[3];
  int G = out_size;
  float* fout = (float*)d_out;

  size_t woff = 0;
  auto alloc = [&](size_t bytes) {
    void* p = (char*)d_ws + woff;
    woff += (bytes + 255) & ~(size_t)255;
    return p;
  };
  float*          bufA  = (float*)alloc((size_t)N * H * 4);
  float*          bufB  = (float*)alloc((size_t)N * H * 4);   // also layer-0 temp (xw)
  unsigned short* xwb   = (unsigned short*)alloc((size_t)N * H * 2);
  double*         dsum  = (double*)alloc((size_t)N * 8);
  float*          dinv  = (float*)alloc((size_t)N * 4);
  int*            cnt   = (int*)alloc((size_t)N * 4);
  int2*           elist = (int2*)alloc((size_t)N * CAP * 8);
  float*          xw    = bufB;   // layer-0 fp32 temp aliases bufB

  const int* erow = eidx;
  const int* ecol = eidx + E;

  hipMemsetAsync(dsum, 0, (size_t)N * 8, stream);

  int nb = (N + 255) / 256;
  int eb = ((E + 255) / 256 + NSWEEP - 1) / NSWEEP * NSWEEP;  // pad: same XCD per chunk across sweeps
  int wgrid = (N + 3) / 4;

  // sweep shift: col range [0,N) split into NSWEEP pieces by high bits
  int shift = 0; while ((NSWEEP << shift) < N) ++shift;       // N=100k, NSWEEP=8 -> shift=14

  dim3 fgrid(eb, 1, NSWEEP);
  k_fillb2<<<fgrid, 256, 0, stream>>>(erow, ecol, ew, dsum, elist, E, shift);
  k_dinv<<<nb, 256, 0, stream>>>(dsum, dinv, cnt, N);

  dim3 ggrid((N + GBM - 1) / GBM, H / GBN);

  // layer 0: aggregate embeddings first (L2-resident gather), then GEMM+bias+relu
  k_agg_emb<<<wgrid, 256, 0, stream>>>(ztab, z, elist, cnt, dinv, xw, N);
  k_gemm<<<ggrid, 256, 0, stream>>>(xw, W0, bufA, N, b0, 1, 0);
  // layer 1: GEMM -> bf16 gather buffer -> aggregate
  k_gemm<<<ggrid, 256, 0, stream>>>(bufA, W1, xwb, N, nullptr, 0, 1);
  k_aggb<<<wgrid, 256, 0, stream>>>(xwb, elist, cnt, dinv, b1, bufB, N, 1);
  // layer 2
  k_gemm<<<ggrid, 256, 0, stream>>>(bufB, W2, xwb, N, nullptr, 0, 1);
  k_aggb<<<wgrid, 256, 0, stream>>>(xwb, elist, cnt, dinv, b2, bufA, N, 0);

  k_head<<<G, 128, 0, stream>>>(bufA, batch, N, l1W, l1b, l2W, l2b, fout, G);
}